// Round 6
// baseline (447.826 us; speedup 1.0000x reference)
//
#include <hip/hip_runtime.h>

#define N 4096            // row length
#define NV (N / 4)        // row length in float4
#define NEG_BIG -9999999.9f
#define SLOTS 8           // per-lane candidate slots

typedef float floatx4 __attribute__((ext_vector_type(4)));

// One wave per row, NO barriers, NO LDS, NO big register arrays.
// Sweep 1: stream x+mask, tracking a running max and a tiny per-lane buffer
//   of candidates z > runmax-1. Since tau* >= rowmax-1, rejected elements
//   have z <= rowmax-1 and contribute exactly 0 to f(u) for all u >= -1, so
//   Newton on the candidate set is bit-identical to Newton on the full row.
// Newton: <=8 register candidates/lane, butterfly-reduced (s,c), ~4-6 iters,
//   wave-uniform early exit. Overflow (ties, all-masked) -> full re-read path.
// Sweep 2: re-stream x+mask (L2/L3-hot) and write out nontemporally.
// The streaming loops carry ~16 live regs -> compiler can keep many loads in
// flight (r4/r5 showed per-wave MLP, not occupancy, is the limiter; barriers
// force vmcnt(0) drains, so this kernel has none).
__global__ __launch_bounds__(256)
void sparsemax_kernel(const float* __restrict__ x,
                      const float* __restrict__ m,
                      float* __restrict__ out,
                      int rows) {
    const int lane = threadIdx.x & 63;
    const int wave = threadIdx.x >> 6;
    const int row  = blockIdx.x * 4 + wave;
    if (row >= rows) return;

    const float4* __restrict__ xr = (const float4*)x + (size_t)row * NV;
    const float4* __restrict__ mr = (const float4*)m + (size_t)row * NV;
    floatx4* __restrict__ outr    = (floatx4*)out + (size_t)row * NV;

    // ---- Sweep 1: running max + candidate collection ----
    float cbuf[SLOTS];
    int   cnt    = 0;
    float runmax = -3.0e38f;

#pragma unroll
    for (int j = 0; j < 16; ++j) {
        float4 xv = xr[j * 64 + lane];
        float4 mv = mr[j * 64 + lane];
        float zz[4];
        zz[0] = (mv.x != 0.0f ? xv.x : NEG_BIG) * 2.0f;
        zz[1] = (mv.y != 0.0f ? xv.y : NEG_BIG) * 2.0f;
        zz[2] = (mv.z != 0.0f ? xv.z : NEG_BIG) * 2.0f;
        zz[3] = (mv.w != 0.0f ? xv.w : NEG_BIG) * 2.0f;
#pragma unroll
        for (int k = 0; k < 4; ++k) {
            float zk = zz[k];
            runmax = fmaxf(runmax, zk);          // include self first
            if (zk > runmax - 1.0f) {            // admit (self always passes)
#pragma unroll
                for (int s_ = 0; s_ < SLOTS; ++s_)
                    if (cnt == s_) cbuf[s_] = zk;
                ++cnt;                           // cnt > SLOTS => overflow
            }
        }
    }

    // Wave-wide row max (butterfly).
    float rmax = runmax;
#pragma unroll
    for (int k = 32; k >= 1; k >>= 1)
        rmax = fmaxf(rmax, __shfl_xor(rmax, k, 64));

    const bool ovf = (__ballot(cnt > SLOTS) != 0ull);   // wave-uniform
    const int  myc = cnt > SLOTS ? SLOTS : cnt;

    // ---- Newton on u (tau = rmax + u), u0 = -1, monotone increasing ----
    float u = -1.0f;
    if (!ovf) {
        for (int it = 0; it < 24; ++it) {
            float s = 0.0f, c = 0.0f;
#pragma unroll
            for (int s_ = 0; s_ < SLOTS; ++s_) {
                if (s_ < myc) {
                    float v = (cbuf[s_] - rmax) - u;
                    if (v > 0.0f) { s += v; c += 1.0f; }
                }
            }
#pragma unroll
            for (int k = 32; k >= 1; k >>= 1) {
                s += __shfl_xor(s, k, 64);
                c += __shfl_xor(c, k, 64);
            }
            float un = u + (s - 1.0f) / c;       // c >= 1 for all u <= u*
            if (!(un > u)) break;                // wave-uniform fixed point
            u = un;
        }
    } else {
        // Rare/adversarial (e.g. all-masked ties): full-row re-read Newton.
        for (int it = 0; it < 24; ++it) {
            float s = 0.0f, c = 0.0f;
            for (int j = 0; j < 16; ++j) {
                float4 xv = xr[j * 64 + lane];
                float4 mv = mr[j * 64 + lane];
                float zz[4];
                zz[0] = (mv.x != 0.0f ? xv.x : NEG_BIG) * 2.0f;
                zz[1] = (mv.y != 0.0f ? xv.y : NEG_BIG) * 2.0f;
                zz[2] = (mv.z != 0.0f ? xv.z : NEG_BIG) * 2.0f;
                zz[3] = (mv.w != 0.0f ? xv.w : NEG_BIG) * 2.0f;
#pragma unroll
                for (int k = 0; k < 4; ++k) {
                    float v = (zz[k] - rmax) - u;
                    if (v > 0.0f) { s += v; c += 1.0f; }
                }
            }
#pragma unroll
            for (int k = 32; k >= 1; k >>= 1) {
                s += __shfl_xor(s, k, 64);
                c += __shfl_xor(c, k, 64);
            }
            float un = u + (s - 1.0f) / c;
            if (!(un > u)) break;
            u = un;
        }
    }

    // All-masked row: reference multiplies by mask -> exact zeros.
    const float live = (rmax == NEG_BIG * 2.0f) ? 0.0f : 1.0f;
    const float thr  = rmax + u;                 // = tau

    // ---- Sweep 2: re-stream (cache-hot) and write output ----
#pragma unroll
    for (int j = 0; j < 16; ++j) {
        floatx4 xv = __builtin_nontemporal_load((const floatx4*)xr + j * 64 + lane);
        floatx4 mv = __builtin_nontemporal_load((const floatx4*)mr + j * 64 + lane);
        floatx4 o;
        o.x = fmaxf((mv.x != 0.0f ? xv.x : NEG_BIG) * 2.0f - thr, 0.0f) * live;
        o.y = fmaxf((mv.y != 0.0f ? xv.y : NEG_BIG) * 2.0f - thr, 0.0f) * live;
        o.z = fmaxf((mv.z != 0.0f ? xv.z : NEG_BIG) * 2.0f - thr, 0.0f) * live;
        o.w = fmaxf((mv.w != 0.0f ? xv.w : NEG_BIG) * 2.0f - thr, 0.0f) * live;
        __builtin_nontemporal_store(o, outr + j * 64 + lane);
    }
}

extern "C" void kernel_launch(void* const* d_in, const int* in_sizes, int n_in,
                              void* d_out, int out_size, void* d_ws, size_t ws_size,
                              hipStream_t stream) {
    const float* x = (const float*)d_in[0];
    const float* m = (const float*)d_in[1];
    float* out = (float*)d_out;
    const int rows = in_sizes[0] / N;            // 8192
    const int blocks = (rows + 3) / 4;           // one wave per row
    sparsemax_kernel<<<blocks, 256, 0, stream>>>(x, m, out, rows);
}

// Round 7
// 319.180 us; speedup vs baseline: 1.4031x; 1.4031x over previous
//
#include <hip/hip_runtime.h>

#define N 4096            // row length
#define NEG_BIG -9999999.9f
#define CAP 256           // candidate buffer capacity per row

typedef float floatx4 __attribute__((ext_vector_type(4)));
typedef __attribute__((address_space(3))) void lds_void;
typedef const __attribute__((address_space(1))) void gbl_void;

// One row per 256-thread block (4 waves, 16 elems/lane).
// x is DMA'd global->LDS via global_load_lds (fire-and-forget: holds no
// dest VGPRs, so the register allocator CANNOT serialize the burst -- the
// failure mode of r4/r5 reg-staged loads). mask streams through 16 regs.
// z[16] lives in regs for the output pass: no global re-read (r6 lesson:
// nontemporal loads bypass cache; FETCH blew up 4.7x), no LDS writeback.
// tau via Newton on the candidate set {z > rmax-1} (provable superset of
// the sparsemax support), all lanes redundant from LDS broadcasts (r4).
// LDS ~17.5 KB -> 8 blocks/CU = 32 waves/CU; VGPR ~50 -> 8-wave tier.
__global__ __launch_bounds__(256)
void sparsemax_kernel(const float* __restrict__ x,
                      const float* __restrict__ m,
                      float* __restrict__ out) {
    const int lane = threadIdx.x & 63;
    const int wave = threadIdx.x >> 6;           // 0..3
    const int row  = blockIdx.x;

    __shared__ float4 xbuf[N / 4];               // 16 KB DMA landing pad
    __shared__ float  cand[CAP];                 // w = z - rmax candidates
    __shared__ float  smax[4];
    __shared__ float2 sparts[2][4];              // fallback partials
    __shared__ int    cnt;
    if (threadIdx.x == 0) cnt = 0;

    const float4* __restrict__ xr = (const float4*)x + (size_t)row * (N / 4);
    const float4* __restrict__ mr = (const float4*)m + (size_t)row * (N / 4);
    float4* __restrict__ outr     = (float4*)out + (size_t)row * (N / 4);

    const int wbase = wave * 64 * 4;             // this wave's quarter (float4 units)

    // ---- Phase 1a: DMA x into LDS, 4 x 1KB per wave, all in flight ----
    // LDS dst is wave-uniform base; HW scatters lane i's 16B to base+i*16,
    // exactly mirroring the global layout (no inner padding -- required).
#pragma unroll
    for (int i = 0; i < 4; ++i) {
        const float4* g = xr + wbase + i * 64 + lane;
        lds_void* l = (lds_void*)(xbuf + wbase + i * 64);
        __builtin_amdgcn_global_load_lds((gbl_void*)g, l, 16, 0, 0);
    }

    // ---- Phase 1b: mask via plain vector loads (L3-warm; NOT nontemporal) ----
    float4 mv0 = mr[wbase + 0 * 64 + lane];
    float4 mv1 = mr[wbase + 1 * 64 + lane];
    float4 mv2 = mr[wbase + 2 * 64 + lane];
    float4 mv3 = mr[wbase + 3 * 64 + lane];

    asm volatile("s_waitcnt vmcnt(0)" ::: "memory");   // DMA + mask complete

    // ---- Phase 2: fold z = (mask ? x : NEG_BIG) * 2 ; z stays in regs ----
    // Each wave reads only the LDS chunk it DMA'd itself -> no barrier needed.
    float z[16];
    {
        float4 xv0 = xbuf[wbase + 0 * 64 + lane];
        float4 xv1 = xbuf[wbase + 1 * 64 + lane];
        float4 xv2 = xbuf[wbase + 2 * 64 + lane];
        float4 xv3 = xbuf[wbase + 3 * 64 + lane];
#define FOLD(k, xv, mv)                                        \
        z[4 * k + 0] = (mv.x != 0.0f ? xv.x : NEG_BIG) * 2.0f; \
        z[4 * k + 1] = (mv.y != 0.0f ? xv.y : NEG_BIG) * 2.0f; \
        z[4 * k + 2] = (mv.z != 0.0f ? xv.z : NEG_BIG) * 2.0f; \
        z[4 * k + 3] = (mv.w != 0.0f ? xv.w : NEG_BIG) * 2.0f;
        FOLD(0, xv0, mv0)
        FOLD(1, xv1, mv1)
        FOLD(2, xv2, mv2)
        FOLD(3, xv3, mv3)
#undef FOLD
    }

    float rmax = -3.0e38f;
#pragma unroll
    for (int i = 0; i < 16; ++i) rmax = fmaxf(rmax, z[i]);
#pragma unroll
    for (int k = 32; k >= 1; k >>= 1)
        rmax = fmaxf(rmax, __shfl_xor(rmax, k, 64));
    if (lane == 0) smax[wave] = rmax;
    __syncthreads();                              // smax + cnt=0 visible
    rmax = fmaxf(fmaxf(smax[0], smax[1]), fmaxf(smax[2], smax[3]));

    // ---- Phase 3: collect candidates w = z - rmax, w > -1 ----
    // (sum_support(z - tau) = 1 implies tau >= rmax - 1, so support is here)
    const float thr0 = rmax - 1.0f;
#pragma unroll
    for (int i = 0; i < 16; ++i) {
        if (z[i] > thr0) {
            int idx = atomicAdd(&cnt, 1);
            if (idx < CAP) cand[idx] = z[i] - rmax;
        }
    }
    __syncthreads();                              // appends visible

    // ---- Phase 4: Newton for u (tau = rmax + u), u0 = -1, monotone up ----
    const int K = cnt;                            // block-uniform
    float u = -1.0f;
    if (K <= CAP) {
        // Tiny-set Newton, identical on every lane (LDS broadcasts).
        for (int it = 0; it < 32; ++it) {
            float s = 0.0f, c = 0.0f;
            for (int j = 0; j < K; ++j) {
                float v = cand[j] - u;
                if (v > 0.0f) { s += v; c += 1.0f; }
            }
            float un = u + (s - 1.0f) / c;        // c >= 1 while u <= u*
            if (!(un > u)) break;                 // exact fixed point
            u = un;
        }
    } else {
        // Rare fallback (e.g. all-masked row: every w == 0, all admitted).
        // K block-uniform -> all waves here; u sequence identical on every
        // wave -> break is block-uniform. Parity double-buffer: 1 barrier/it.
        int parity = 0;
        for (int it = 0; it < 32; ++it) {
            float s = 0.0f, c = 0.0f;
#pragma unroll
            for (int i = 0; i < 16; ++i) {
                float v = (z[i] - rmax) - u;
                if (v > 0.0f) { s += v; c += 1.0f; }
            }
#pragma unroll
            for (int k = 32; k >= 1; k >>= 1) {
                s += __shfl_xor(s, k, 64);
                c += __shfl_xor(c, k, 64);
            }
            if (lane == 0) sparts[parity][wave] = make_float2(s, c);
            __syncthreads();
            float S = 0.0f, C = 0.0f;
#pragma unroll
            for (int w = 0; w < 4; ++w) {
                float2 p = sparts[parity][w];
                S += p.x; C += p.y;
            }
            float un = u + (S - 1.0f) / C;
            parity ^= 1;
            if (!(un > u)) break;
            u = un;
        }
    }

    // ---- Phase 5: output from register z; nontemporal STORES only ----
    // All-masked row: reference multiplies by mask -> exact zeros.
    const float live = (rmax == NEG_BIG * 2.0f) ? 0.0f : 1.0f;
    const float thr  = rmax + u;                  // = tau

#pragma unroll
    for (int j = 0; j < 4; ++j) {
        floatx4 o;
        o.x = fmaxf(z[4 * j + 0] - thr, 0.0f) * live;
        o.y = fmaxf(z[4 * j + 1] - thr, 0.0f) * live;
        o.z = fmaxf(z[4 * j + 2] - thr, 0.0f) * live;
        o.w = fmaxf(z[4 * j + 3] - thr, 0.0f) * live;
        __builtin_nontemporal_store(o, (floatx4*)&outr[wbase + j * 64 + lane]);
    }
}

extern "C" void kernel_launch(void* const* d_in, const int* in_sizes, int n_in,
                              void* d_out, int out_size, void* d_ws, size_t ws_size,
                              hipStream_t stream) {
    const float* x = (const float*)d_in[0];
    const float* m = (const float*)d_in[1];
    float* out = (float*)d_out;
    const int rows = in_sizes[0] / N;             // 8192
    sparsemax_kernel<<<rows, 256, 0, stream>>>(x, m, out);
}

// Round 8
// 316.123 us; speedup vs baseline: 1.4166x; 1.0097x over previous
//
#include <hip/hip_runtime.h>

#define N 4096            // row length
#define NEG_BIG -9999999.9f
#define CAP 16            // candidate slots (register-resident in Newton)

typedef float floatx4 __attribute__((ext_vector_type(4)));

// One row per 1024-thread block (16 waves, 4 elems/lane).
// Minimal per-lane serial structure: exactly 2 coalesced float4 loads issued
// back-to-back (no register array to serialize -- r4/r5/r7 showed the
// allocator otherwise re-serializes load bursts), one drain, one store.
// tau via Newton on the candidate set {z > rmax-1} (provable superset of the
// sparsemax support: sum_support(z-tau)=1 => tau >= rmax-1, and excluded
// elements contribute exactly 0 to f(u) for all u >= -1). Candidates are
// copied LDS->registers once; the Newton loop runs entirely in VGPRs.
// Overflow (e.g. all-masked tie rows) -> block-wide butterfly fallback.
__global__ __launch_bounds__(1024)
void sparsemax_kernel(const float* __restrict__ x,
                      const float* __restrict__ m,
                      float* __restrict__ out) {
    const int tid  = threadIdx.x;          // 0..1023 = float4 index in row
    const int lane = tid & 63;
    const int wid  = tid >> 6;             // 0..15
    const int row  = blockIdx.x;

    __shared__ float  smax[16];
    __shared__ float  cand[CAP];
    __shared__ float2 sparts[2][16];       // fallback partials
    __shared__ int    cnt;
    if (tid == 0) cnt = 0;

    const float4* __restrict__ xr = (const float4*)x + (size_t)row * (N / 4);
    const float4* __restrict__ mr = (const float4*)m + (size_t)row * (N / 4);
    floatx4* __restrict__ outr    = (floatx4*)out + (size_t)row * (N / 4);

    // ---- Two loads, issued together ----
    float4 xv = xr[tid];
    float4 mv = mr[tid];

    // z = (mask ? x : NEG_BIG) * 2   (/(1-TEMP), TEMP=0.5)
    float z[4];
    z[0] = (mv.x != 0.0f ? xv.x : NEG_BIG) * 2.0f;
    z[1] = (mv.y != 0.0f ? xv.y : NEG_BIG) * 2.0f;
    z[2] = (mv.z != 0.0f ? xv.z : NEG_BIG) * 2.0f;
    z[3] = (mv.w != 0.0f ? xv.w : NEG_BIG) * 2.0f;

    // ---- Block max: wave butterfly, then 16 broadcast LDS reads ----
    float wmax = fmaxf(fmaxf(z[0], z[1]), fmaxf(z[2], z[3]));
#pragma unroll
    for (int k = 32; k >= 1; k >>= 1)
        wmax = fmaxf(wmax, __shfl_xor(wmax, k, 64));
    if (lane == 0) smax[wid] = wmax;
    __syncthreads();                       // smax + cnt=0 visible
    float rmax = smax[0];
#pragma unroll
    for (int w = 1; w < 16; ++w) rmax = fmaxf(rmax, smax[w]);

    // ---- Candidate collection: w = z - rmax, admit w > -1 ----
    const float thr0 = rmax - 1.0f;
#pragma unroll
    for (int i = 0; i < 4; ++i) {
        if (z[i] > thr0) {
            int idx = atomicAdd(&cnt, 1);
            if (idx < CAP) cand[idx] = z[i] - rmax;
        }
    }
    __syncthreads();                       // appends visible
    const int K = cnt;                     // block-uniform

    // ---- Newton for u (tau = rmax + u), u0 = -1, monotone increasing ----
    float u = -1.0f;
    if (K <= CAP) {
        // Pull candidates into registers ONCE (broadcast reads, pipelined);
        // empty slots get -inf-ish so they never contribute.
        float cr[CAP];
#pragma unroll
        for (int j = 0; j < CAP; ++j)
            cr[j] = (j < K) ? cand[j] : -3.0e38f;
        for (int it = 0; it < 32; ++it) {
            float s = 0.0f, c = 0.0f;
#pragma unroll
            for (int j = 0; j < CAP; ++j) {
                float v = cr[j] - u;
                if (v > 0.0f) { s += v; c += 1.0f; }
            }
            float un = u + (s - 1.0f) / c; // c >= 1 while u <= u*
            if (!(un > u)) break;          // exact fixed point (uniform)
            u = un;
        }
    } else {
        // Rare fallback (e.g. all-masked row: all w==0 admitted). K is
        // block-uniform -> all threads here; u sequence identical on every
        // thread -> barriers and break are block-uniform. Parity
        // double-buffer: one barrier per iteration.
        int parity = 0;
        for (int it = 0; it < 32; ++it) {
            float s = 0.0f, c = 0.0f;
#pragma unroll
            for (int i = 0; i < 4; ++i) {
                float v = (z[i] - rmax) - u;
                if (v > 0.0f) { s += v; c += 1.0f; }
            }
#pragma unroll
            for (int k = 32; k >= 1; k >>= 1) {
                s += __shfl_xor(s, k, 64);
                c += __shfl_xor(c, k, 64);
            }
            if (lane == 0) sparts[parity][wid] = make_float2(s, c);
            __syncthreads();
            float S = 0.0f, C = 0.0f;
#pragma unroll
            for (int w = 0; w < 16; ++w) {
                float2 p = sparts[parity][w];
                S += p.x; C += p.y;
            }
            float un = u + (S - 1.0f) / C;
            parity ^= 1;
            if (!(un > u)) break;
            u = un;
        }
    }

    // ---- Output; masked entries hit the relu floor (z-tau << 0) ----
    // All-masked row: reference multiplies by mask -> exact zeros via live.
    const float live = (rmax == NEG_BIG * 2.0f) ? 0.0f : 1.0f;
    const float thr  = rmax + u;           // = tau

    floatx4 o;
    o.x = fmaxf(z[0] - thr, 0.0f) * live;
    o.y = fmaxf(z[1] - thr, 0.0f) * live;
    o.z = fmaxf(z[2] - thr, 0.0f) * live;
    o.w = fmaxf(z[3] - thr, 0.0f) * live;
    __builtin_nontemporal_store(o, outr + tid);
}

extern "C" void kernel_launch(void* const* d_in, const int* in_sizes, int n_in,
                              void* d_out, int out_size, void* d_ws, size_t ws_size,
                              hipStream_t stream) {
    const float* x = (const float*)d_in[0];
    const float* m = (const float*)d_in[1];
    float* out = (float*)d_out;
    const int rows = in_sizes[0] / N;      // 8192
    sparsemax_kernel<<<rows, 1024, 0, stream>>>(x, m, out);
}